// Round 3
// baseline (88.540 us; speedup 1.0000x reference)
//
#include <hip/hip_runtime.h>

// PS-ROI Align: img (1,20,20,1568) f32, rois (1,8192,4) f32 -> out (1,8192,7,7,32) f32
// f[b,y,x,a] = img[(y*20+x)*1568 + b*32 + a];  out[r,p,q,a], bin = p*7+q (x<-p, y<-q).
//
// R3: barrier-free, LDS-free. R1/R2 proved the kernel is not LDS-conflict-bound;
// the residual cost model says it is phase-serialization (stage -> vmcnt(0)+barrier
// -> DS burst -> store burst) of 2 monolithic blocks/CU. img is 2.5 MB = fully
// L2-resident per XCD, so staging is pure overhead (common-mistake #7):
//   - one work item = (roi, bin, alpha-quad); 8-lane group per (roi,bin)
//   - each of the 9 cell reads is ONE aligned 128 B L2 transaction per group
//     (8 lanes x 16 B consecutive), no LDS round-trip
//   - weights computed per-lane from a broadcast rois read (no producer phase)
//   - no __syncthreads anywhere; 12,544 small blocks stream freely
//   - nt-stores (evict-first) protect the img L2 set from 51.4 MB of write traffic

#define CH    1568
#define ROW_F (20 * CH)        // floats per image row (y stride)

typedef float vf4 __attribute__((ext_vector_type(4)));

// Distribute the two samples' 1D bilinear weights (validity mask + reference
// clamping semantics) onto 3 consecutive cells starting at base b.
__device__ __forceinline__ void axis_weights(float s0, float s1,
                                             int& b, float& W0, float& W1, float& W2)
{
    const float f0 = floorf(s0), f1 = floorf(s1);
    const float w0 = s0 - f0,    w1 = s1 - f1;
    const float v0 = (s0 >= 0.f && s0 <= 19.f) ? 1.f : 0.f;
    const float v1 = (s1 >= 0.f && s1 <= 19.f) ? 1.f : 0.f;
    const int c00 = min(max((int)f0, 0), 19);
    const int c01 = min(c00 + 1, 19);
    const int c10 = min(max((int)f1, 0), 19);   // s1 > s0 => c10 in {c00, c00+1}
    const int c11 = min(c10 + 1, 19);
    b = c00;
    W0 = v0 * (1.f - w0);
    W1 = 0.f; W2 = 0.f;
    float t = v0 * w0;
    if (c01 == b) W0 += t; else W1 += t;
    t = v1 * (1.f - w1);
    if (c10 == b) W0 += t; else W1 += t;
    t = v1 * w1;
    const int d = c11 - b;
    W0 += (d == 0) ? t : 0.f;
    W1 += (d == 1) ? t : 0.f;
    W2 += (d == 2) ? t : 0.f;
}

__global__ __launch_bounds__(256, 6) void psroi_kernel(
    const float* __restrict__ img,
    const float* __restrict__ rois,
    float* __restrict__ out)
{
    const unsigned t     = threadIdx.x;
    const unsigned bin   = blockIdx.x >> 8;       // 0..48
    const unsigned chunk = blockIdx.x & 255u;     // 0..255, 32 ROIs each
    const unsigned p     = bin / 7u;              // bin_x (drives x)
    const unsigned q     = bin - p * 7u;          // bin_y (drives y)

    const unsigned g = t >> 3;                    // roi within chunk 0..31
    const unsigned s = t & 7u;                    // alpha quad 0..7
    const unsigned r = chunk * 32u + g;           // global roi

    // rois read: 8 lanes share one address (broadcast), wave covers 8 consecutive
    // vf4s = one coalesced 128 B transaction.
    const vf4 roi = ((const vf4*)rois)[r];
    const float step_x = roi.z * (1.0f / 7.0f);
    const float step_y = roi.w * (1.0f / 7.0f);
    const float sc  = 19.0f / 20.0f;
    const float sx0 = (roi.x + (float)p * step_x) * sc;
    const float sx1 = (roi.x + (float)(p + 1) * step_x) * sc;
    const float sy0 = (roi.y + (float)q * step_y) * sc;
    const float sy1 = (roi.y + (float)(q + 1) * step_y) * sc;

    int bx, by;
    float WX[3], WY[3];
    axis_weights(sx0, sx1, bx, WX[0], WX[1], WX[2]);
    axis_weights(sy0, sy1, by, WY[0], WY[1], WY[2]);
    WY[0] *= 0.25f; WY[1] *= 0.25f; WY[2] *= 0.25f;   // fold the /4 sample mean

    // float offsets of the 3x3 cell window (u24-mul friendly: max 595,840)
    const unsigned colf[3] = { (unsigned)bx * (unsigned)CH,
                               (unsigned)min(bx + 1, 19) * (unsigned)CH,
                               (unsigned)min(bx + 2, 19) * (unsigned)CH };
    const unsigned rowf[3] = { (unsigned)by * (unsigned)ROW_F,
                               (unsigned)min(by + 1, 19) * (unsigned)ROW_F,
                               (unsigned)min(by + 2, 19) * (unsigned)ROW_F };

    // lane's quad within the bin's 128 B cell line
    const float* base = img + bin * 32u + s * 4u;

    vf4 acc = { 0.f, 0.f, 0.f, 0.f };
#pragma unroll
    for (int i = 0; i < 3; ++i) {
#pragma unroll
        for (int j = 0; j < 3; ++j) {
            const vf4 v = *(const vf4*)(base + rowf[i] + colf[j]);
            acc += (WY[i] * WX[j]) * v;
        }
    }

    // out float index = r*1568 + bin*32 + s*4; each 8-lane group stores a
    // contiguous, 128 B-aligned line.
    const size_t ob = (size_t)r * 1568u + bin * 32u + s * 4u;
    __builtin_nontemporal_store(acc, (vf4*)(out + ob));
}

extern "C" void kernel_launch(void* const* d_in, const int* in_sizes, int n_in,
                              void* d_out, int out_size, void* d_ws, size_t ws_size,
                              hipStream_t stream) {
    const float* img  = (const float*)d_in[0];
    const float* rois = (const float*)d_in[1];
    float* out = (float*)d_out;
    // grid = 49 bins * 256 chunks of 32 ROIs = 12,544 blocks of 256 threads
    hipLaunchKernelGGL(psroi_kernel, dim3(49 * 256), dim3(256), 0, stream, img, rois, out);
}

// Round 4
// 80.928 us; speedup vs baseline: 1.0940x; 1.0940x over previous
//
#include <hip/hip_runtime.h>

// PS-ROI Align: img (1,20,20,1568) f32, rois (1,8192,4) f32 -> out (1,8192,7,7,32) f32
// f[b,y,x,a] = img[(y*20+x)*1568 + b*32 + a];  out[r,p,q,a], bin = p*7+q (x<-p, y<-q).
//
// R4 = R2 (LDS, conflict-free-by-construction 8-lane groups) + split-source reads:
//   window rows 0,1 come from LDS; row 2 comes from the VMEM path (img is 2.5 MB,
//   L2-resident) predicated on WY[2] != 0 (exactly zero for ~46% of (roi,bin):
//   skipping contributes exactly 0, bit-identical). This moves 1/3 of the window
//   traffic off the DS pipe (the max-term: 25 -> 19 b128 ops/thread-slot) onto the
//   post-Phase-A-idle VMEM pipe.
// Cost model: DS ~9.6 us || HBM store 8.2 us || VMEM ~2.3 us || VALU ~7 us.

#define CH    1568
#define ROW_F (20 * CH)
#define CELLS 400
#define ROIS_PER_BLOCK 256
#define IMG_F (CELLS * 32)              // 12800 floats = 51.2 KB
#define PKOFF IMG_F                     // packet area: 256 rois * 8 floats = 8 KB
#define LDS_FLOATS (IMG_F + ROIS_PER_BLOCK * 8)   // 59,392 B

typedef float vf4 __attribute__((ext_vector_type(4)));

// Distribute the two samples' 1D bilinear weights (validity mask + reference
// clamping semantics) onto 3 consecutive cells starting at base b.
__device__ __forceinline__ void axis_weights(float s0, float s1,
                                             int& b, float& W0, float& W1, float& W2)
{
    const float f0 = floorf(s0), f1 = floorf(s1);
    const float w0 = s0 - f0,    w1 = s1 - f1;
    const float v0 = (s0 >= 0.f && s0 <= 19.f) ? 1.f : 0.f;
    const float v1 = (s1 >= 0.f && s1 <= 19.f) ? 1.f : 0.f;
    const int c00 = min(max((int)f0, 0), 19);
    const int c01 = min(c00 + 1, 19);
    const int c10 = min(max((int)f1, 0), 19);   // s1 > s0 => c10 in {c00, c00+1}
    const int c11 = min(c10 + 1, 19);
    b = c00;
    W0 = v0 * (1.f - w0);
    W1 = 0.f; W2 = 0.f;
    float t = v0 * w0;
    if (c01 == b) W0 += t; else W1 += t;
    t = v1 * (1.f - w1);
    if (c10 == b) W0 += t; else W1 += t;
    t = v1 * w1;
    const int d = c11 - b;
    W0 += (d == 0) ? t : 0.f;
    W1 += (d == 1) ? t : 0.f;
    W2 += (d == 2) ? t : 0.f;
}

__global__ __launch_bounds__(1024, 8) void psroi_kernel(
    const float* __restrict__ img,
    const float* __restrict__ rois,
    float* __restrict__ out)
{
    __shared__ __align__(16) float lds[LDS_FLOATS];

    const unsigned t     = threadIdx.x;
    const unsigned bin   = blockIdx.x;        // 0..48
    const unsigned chunk = blockIdx.y;        // 0..31
    const unsigned p     = bin / 7u;          // bin_x (drives x)
    const unsigned q     = bin - p * 7u;      // bin_y (drives y)

    // ---- Phase A: stage bin slice into LDS (3200 float4, 1024 threads) ----
    {
        const float* src = img + bin * 32u;
        for (unsigned idx = t; idx < CELLS * 8u; idx += 1024u) {
            const unsigned cell = idx >> 3;       // 0..399
            const unsigned sub  = idx & 7u;       // float4 within cell
            const vf4 v = *(const vf4*)(src + (size_t)cell * CH + sub * 4u);
            *(vf4*)(&lds[cell * 32u + sub * 4u]) = v;
        }
    }

    // ---- Phase B: threads 0..255 compute one packet per ROI ----
    if (t < ROIS_PER_BLOCK) {
        const unsigned r = chunk * ROIS_PER_BLOCK + t;
        const vf4 roi = ((const vf4*)rois)[r];
        const float step_x = roi.z * (1.0f / 7.0f);
        const float step_y = roi.w * (1.0f / 7.0f);
        const float s = 19.0f / 20.0f;
        const float sx0 = (roi.x + (float)p * step_x) * s;
        const float sx1 = (roi.x + (float)(p + 1) * step_x) * s;
        const float sy0 = (roi.y + (float)q * step_y) * s;
        const float sy1 = (roi.y + (float)(q + 1) * step_y) * s;

        int bx, by;
        float WX0, WX1, WX2, WY0, WY1, WY2;
        axis_weights(sx0, sx1, bx, WX0, WX1, WX2);
        axis_weights(sy0, sy1, by, WY0, WY1, WY2);

        vf4 p0, p1;
        p0.x = __int_as_float(bx);
        p0.y = __int_as_float(by);
        p0.z = WX0; p0.w = WX1;
        p1.x = WX2;
        p1.y = WY0 * 0.25f; p1.z = WY1 * 0.25f; p1.w = WY2 * 0.25f;  // fold mean
        *(vf4*)(&lds[PKOFF + t * 8u])     = p0;
        *(vf4*)(&lds[PKOFF + t * 8u + 4]) = p1;
    }

    __syncthreads();

    // ---- Phase C: 8 lanes per ROI, 2 ROIs per thread ----
    const unsigned g  = t >> 3;              // group 0..127
    const unsigned s  = t & 7u;              // alpha quad selector 0..7
    const unsigned sb = s << 4;              // byte offset within 128 B cell line
    const char* ldsb = (const char*)lds;
    const float* gbase = img + bin * 32u + s * 4u;   // global path (L2-hot)

#pragma unroll
    for (int pass = 0; pass < 2; ++pass) {
        const unsigned rl = g + (unsigned)pass * 128u;

        const float* pkp = &lds[PKOFF + rl * 8u];   // 8-lane broadcast read
        const vf4 p0 = *(const vf4*)pkp;
        const vf4 p1 = *(const vf4*)(pkp + 4);
        const int bx = __float_as_int(p0.x);
        const int by = __float_as_int(p0.y);
        const float WX[3] = { p0.z, p0.w, p1.x };
        const float WY0 = p1.y, WY1 = p1.z, WY2 = p1.w;

        const unsigned c0 = (unsigned)bx;
        const unsigned c1 = (unsigned)min(bx + 1, 19);
        const unsigned c2 = (unsigned)min(bx + 2, 19);
        const unsigned colb[3] = { c0 * 128u + sb, c1 * 128u + sb, c2 * 128u + sb };
        const unsigned rowb0 = (unsigned)by * 2560u;
        const unsigned rowb1 = (unsigned)min(by + 1, 19) * 2560u;

        vf4 acc = { 0.f, 0.f, 0.f, 0.f };
        // rows 0,1 from LDS: 8-lane group reads a full 128 B cell line -> all 32
        // banks exactly once -> conflict-free for any data-dependent address.
#pragma unroll
        for (int j = 0; j < 3; ++j) {
            const vf4 v0 = *(const vf4*)(ldsb + (rowb0 + colb[j]));
            acc += (WY0 * WX[j]) * v0;
            const vf4 v1 = *(const vf4*)(ldsb + (rowb1 + colb[j]));
            acc += (WY1 * WX[j]) * v1;
        }
        // row 2 from global (L2-resident), skipped when its weight is exactly 0
        // (~46% of cases; contributes exactly 0 otherwise -> bit-identical).
        if (WY2 != 0.f) {
            const float* g2 = gbase + (unsigned)min(by + 2, 19) * (unsigned)ROW_F;
            const vf4 u0 = *(const vf4*)(g2 + c0 * (unsigned)CH);
            const vf4 u1 = *(const vf4*)(g2 + c1 * (unsigned)CH);
            const vf4 u2 = *(const vf4*)(g2 + c2 * (unsigned)CH);
            acc += (WY2 * WX[0]) * u0;
            acc += (WY2 * WX[1]) * u1;
            acc += (WY2 * WX[2]) * u2;
        }

        // 8-lane group writes contiguous 128 B: floats [bin*32 .. bin*32+31]
        const size_t ob = ((size_t)chunk * ROIS_PER_BLOCK + rl) * (49u * 32u)
                        + bin * 32u + s * 4u;
        __builtin_nontemporal_store(acc, (vf4*)(out + ob));
    }
}

extern "C" void kernel_launch(void* const* d_in, const int* in_sizes, int n_in,
                              void* d_out, int out_size, void* d_ws, size_t ws_size,
                              hipStream_t stream) {
    const float* img  = (const float*)d_in[0];
    const float* rois = (const float*)d_in[1];
    float* out = (float*)d_out;
    // grid = (49 bins, 32 chunks of 256 ROIs), 1024 threads
    hipLaunchKernelGGL(psroi_kernel, dim3(49, 32), dim3(1024), 0, stream, img, rois, out);
}